// Round 11
// baseline (236.889 us; speedup 1.0000x reference)
//
#include <hip/hip_runtime.h>
#include <hip/hip_bf16.h>

// Problem constants
#define BB    8
#define NNODE 128
#define CIN   512
#define HH    8
#define DDIM  64
#define HD    512   // H*D

typedef float f32x4 __attribute__((ext_vector_type(4)));
typedef short bf16x8 __attribute__((ext_vector_type(8)));
typedef unsigned int u32x4 __attribute__((ext_vector_type(4)));

#define AS1 __attribute__((address_space(1)))
#define AS3 __attribute__((address_space(3)))

static __device__ __forceinline__ unsigned short f2bf(float f) {
    unsigned int x = __float_as_uint(f);
    x = x + 0x7FFFu + ((x >> 16) & 1u);
    return (unsigned short)(x >> 16);
}

// fast f32x4 pair -> bf16x8 via v_cvt_pk_bf16_f32 (RNE)
static __device__ __forceinline__ bf16x8 cvt8(f32x4 a, f32x4 b) {
    union { u32x4 u; bf16x8 h8; } cv;
    asm("v_cvt_pk_bf16_f32 %0, %1, %2" : "=v"(cv.u[0]) : "v"(a[0]), "v"(a[1]));
    asm("v_cvt_pk_bf16_f32 %0, %1, %2" : "=v"(cv.u[1]) : "v"(a[2]), "v"(a[3]));
    asm("v_cvt_pk_bf16_f32 %0, %1, %2" : "=v"(cv.u[2]) : "v"(b[0]), "v"(b[1]));
    asm("v_cvt_pk_bf16_f32 %0, %1, %2" : "=v"(cv.u[3]) : "v"(b[2]), "v"(b[3]));
    return cv.h8;
}

// ---------------------------------------------------------------------------
// Kernel 1: tiled transpose+convert Wq/Wk/Wv [c][hd] f32 -> WT [m][hd][c] bf16
// ---------------------------------------------------------------------------
__global__ __launch_bounds__(256) void k_wt(
    const float* __restrict__ Wq, const float* __restrict__ Wk,
    const float* __restrict__ Wv,
    unsigned short* __restrict__ WT)
{
    __shared__ unsigned short tile[64][72];
    const int cb = blockIdx.x;
    const int hb = blockIdx.y;
    const int m  = blockIdx.z;          // 0=Wq,1=Wk,2=Wv
    const float* W = (m == 0) ? Wq : (m == 1) ? Wk : Wv;
    const int t = threadIdx.x;

#pragma unroll
    for (int it = 0; it < 4; ++it) {
        int row = it * 16 + (t >> 4);
        int col = (t & 15) * 4;
        f32x4 v = *reinterpret_cast<const f32x4*>(W + (size_t)(cb * 64 + row) * HD + hb * 64 + col);
        tile[row][col + 0] = f2bf(v[0]);
        tile[row][col + 1] = f2bf(v[1]);
        tile[row][col + 2] = f2bf(v[2]);
        tile[row][col + 3] = f2bf(v[3]);
    }
    __syncthreads();

#pragma unroll
    for (int it = 0; it < 4; ++it) {
        int hd = it * 16 + (t >> 4);
        int c  = (t & 15) * 4;
        unsigned long long pk =
            (unsigned long long)(unsigned short)tile[c + 0][hd] |
            ((unsigned long long)(unsigned short)tile[c + 1][hd] << 16) |
            ((unsigned long long)(unsigned short)tile[c + 2][hd] << 32) |
            ((unsigned long long)(unsigned short)tile[c + 3][hd] << 48);
        *reinterpret_cast<unsigned long long*>(
            &WT[((size_t)(m + 1) * HD + hb * 64 + hd) * CIN + cb * 64 + c]) = pk;
    }
}

// ---------------------------------------------------------------------------
// Kernel 2: QKV projections via bf16 MFMA (unchanged).
// ---------------------------------------------------------------------------
__global__ __launch_bounds__(256) void k_qkv(
    const float* __restrict__ hin,
    const unsigned short* __restrict__ WT,
    const float* __restrict__ bq, const float* __restrict__ bk, const float* __restrict__ bv,
    float* __restrict__ Qo, float* __restrict__ Ko, float* __restrict__ Vo)
{
    __shared__ unsigned short hs[64][520];
    const int rt = blockIdx.x;
    const int ct = blockIdx.y;
    const int m  = blockIdx.z;
    const int t  = threadIdx.x;
    const int w  = t >> 6;
    const int l  = t & 63;
    const int g  = l >> 4;
    const int c15 = l & 15;
    const float* bias = (m == 0) ? bq : (m == 1) ? bk : bv;
    float* Out = (m == 0) ? Qo : (m == 1) ? Ko : Vo;
    const unsigned short* Wm = WT + (size_t)(m + 1) * HD * CIN;
    const int rowbase = rt * 64;
    const int colbase = ct * 64;

#pragma unroll
    for (int q = 0; q < 32; ++q) {
        int f = q * 1024 + t * 4;
        int row = f >> 9;
        int c = f & 511;
        f32x4 hv = *reinterpret_cast<const f32x4*>(hin + (size_t)(rowbase + row) * CIN + c);
        unsigned long long pk =
            (unsigned long long)f2bf(hv[0]) |
            ((unsigned long long)f2bf(hv[1]) << 16) |
            ((unsigned long long)f2bf(hv[2]) << 32) |
            ((unsigned long long)f2bf(hv[3]) << 48);
        *reinterpret_cast<unsigned long long*>(&hs[row][c]) = pk;
    }
    __syncthreads();

    f32x4 acc[4];
#pragma unroll
    for (int nf = 0; nf < 4; ++nf) acc[nf] = (f32x4){0.f, 0.f, 0.f, 0.f};

#pragma unroll
    for (int kt = 0; kt < 16; ++kt) {
        bf16x8 afr = *reinterpret_cast<const bf16x8*>(&hs[w * 16 + c15][kt * 32 + g * 8]);
#pragma unroll
        for (int nf = 0; nf < 4; ++nf) {
            const unsigned short* wp = Wm + (size_t)(colbase + nf * 16 + c15) * CIN + kt * 32 + g * 8;
            bf16x8 bfr = *reinterpret_cast<const bf16x8*>(wp);
            acc[nf] = __builtin_amdgcn_mfma_f32_16x16x32_bf16(afr, bfr, acc[nf], 0, 0, 0);
        }
    }

    const float scale = (m == 1) ? 0.125f : 1.0f;
#pragma unroll
    for (int nf = 0; nf < 4; ++nf) {
        int col = colbase + nf * 16 + c15;
        float bv_ = bias[col];
#pragma unroll
        for (int r = 0; r < 4; ++r) {
            int row = rowbase + w * 16 + g * 4 + r;
            Out[(size_t)row * HD + col] = (acc[nf][r] + bv_) * scale;
        }
    }
}

// ---------------------------------------------------------------------------
// Kernel 1b: We -> WTB, B-fragment-linear for 16x16x32 (K = c, N = hd).
// WTB[((h*8+ct)*8 + kt*4+nf)*512 + l*8 + i]
//   = bf16(We[ct*64 + kt*32 + (l>>4)*8 + i][h*64 + nf*16 + (l&15)])
// ---------------------------------------------------------------------------
__global__ __launch_bounds__(256) void k_wtb(
    const float* __restrict__ We, unsigned short* __restrict__ WTB)
{
    const int h  = blockIdx.x;          // 0..7
    const int ct = blockIdx.y;          // 0..7
    const int t  = threadIdx.x;
#pragma unroll
    for (int it = 0; it < 2; ++it) {
        int s  = it * 256 + t;          // (kt,nf,l): 2*4*64 = 512
        int kt = s >> 8, nf = (s >> 6) & 3, l = s & 63;
        int c0 = ct * 64 + kt * 32 + (l >> 4) * 8;
        int hd = h * 64 + nf * 16 + (l & 15);
        bf16x8 v;
#pragma unroll
        for (int i = 0; i < 8; ++i)
            v[i] = (short)f2bf(We[(size_t)(c0 + i) * HD + hd]);
        size_t off = ((size_t)(h * 8 + ct) * 8 + kt * 4 + nf) * 512 + l * 8;
        *reinterpret_cast<bf16x8*>(&WTB[off]) = v;
    }
}

// ---------------------------------------------------------------------------
// Kernel 3 v11: block = (bi, j-half), 2048 blocks, 512 thr = 8 waves = heads.
// acc[4][4]=64 + B[8]=32 -> ~120 regs/wave => 4 waves/SIMD => 2 blocks/CU
// co-resident (the r10 machinery, sized for cross-block overlap).
// 8 phases of 64 c; e f32 via swizzled global_load_lds into 3 x 16KB buffers,
// 2-phase-deep FIFO: [S(ct+1)][B(ct)][S(ct+2)], waits vmcnt(2).
// ---------------------------------------------------------------------------
__global__ __launch_bounds__(512, 2) void k_main(
    const float* __restrict__ e, const float* __restrict__ k_RW,
    const unsigned short* __restrict__ WTB, const float* __restrict__ be,
    const float* __restrict__ Qw, const float* __restrict__ Kw,
    const float* __restrict__ Vw, float* __restrict__ PN, float* __restrict__ PD)
{
    __shared__ float e_s[3 * 4096];     // 3 x 16 KB tiles [jl 0..63][swizzled c]
    __shared__ float s_lds[8][64];

    const int bx   = blockIdx.x;
    const int bi   = bx >> 1;           // b*128 + i
    const int half = bx & 1;
    const int b    = bi >> 7;
    const int t    = threadIdx.x;
    const int h    = t >> 6;            // wave id == head
    const int l    = t & 63;
    const int g    = l >> 4;
    const int c15  = l & 15;

    const float* ebase = e + ((size_t)bi * NNODE + half * 64) * CIN;

    f32x4 acc[4][4];
#pragma unroll
    for (int mf = 0; mf < 4; ++mf)
#pragma unroll
        for (int nf = 0; nf < 4; ++nf)
            acc[mf][nf] = (f32x4){0.f, 0.f, 0.f, 0.f};

    // per-lane LDS read sub-offsets: granule = (kt*8 + g*2 + p) ^ c15 (16B units)
    const int s00 = ((g * 2 + 0) ^ c15) << 4;
    const int s01 = ((g * 2 + 1) ^ c15) << 4;
    const int s10 = ((8 + g * 2 + 0) ^ c15) << 4;
    const int s11 = ((8 + g * 2 + 1) ^ c15) << 4;

    // STAGE(TT): wave h stages rows [h*8, h*8+8) of 64x64 f32 tile TT.
    // instr q: rows h*8+q*4+g; dest linear; source granule pre-swizzled by
    // key = row & 15 = (h&1)*8 + q*4 + g (read side XORs by c15 = row&15).
#define STAGE(TT) do {                                                          \
        _Pragma("unroll")                                                       \
        for (int q_ = 0; q_ < 2; ++q_) {                                        \
            const int key_ = ((h & 1) << 3) + q_ * 4 + g;                       \
            const float* src_ = ebase + (size_t)(h * 8 + q_ * 4 + g) * CIN      \
                                + (TT) * 64 + ((c15 ^ key_) << 2);              \
            __builtin_amdgcn_global_load_lds(                                   \
                (const AS1 unsigned int*)src_,                                  \
                (AS3 unsigned int*)((char*)&e_s[0] + ((TT) % 3) * 16384         \
                                    + h * 2048 + q_ * 1024), 16, 0, 0);         \
        }                                                                       \
    } while (0)

#define LOADB(CT) do {                                                          \
        const unsigned short* bp_ = WTB + ((size_t)(h * 8 + (CT)) * 8) * 512 + l * 8; \
        _Pragma("unroll")                                                       \
        for (int f_ = 0; f_ < 8; ++f_)                                          \
            wB[f_] = *reinterpret_cast<const bf16x8*>(bp_ + f_ * 512);          \
    } while (0)

#define COMPUTE(CT) do {                                                        \
        const char* ebuf_ = (const char*)&e_s[0] + ((CT) % 3) * 16384;          \
        _Pragma("unroll")                                                       \
        for (int mf_ = 0; mf_ < 4; ++mf_) {                                     \
            const char* rp_ = ebuf_ + (mf_ * 16 + c15) * 256;                   \
            bf16x8 a0_ = cvt8(*(const f32x4*)(rp_ + s00),                       \
                              *(const f32x4*)(rp_ + s01));                      \
            bf16x8 a1_ = cvt8(*(const f32x4*)(rp_ + s10),                       \
                              *(const f32x4*)(rp_ + s11));                      \
            _Pragma("unroll")                                                   \
            for (int nf_ = 0; nf_ < 4; ++nf_) {                                 \
                acc[mf_][nf_] = __builtin_amdgcn_mfma_f32_16x16x32_bf16(        \
                    a0_, wB[nf_], acc[mf_][nf_], 0, 0, 0);                      \
                acc[mf_][nf_] = __builtin_amdgcn_mfma_f32_16x16x32_bf16(        \
                    a1_, wB[4 + nf_], acc[mf_][nf_], 0, 0, 0);                  \
            }                                                                   \
        }                                                                       \
    } while (0)

    // Phase ct: entry wait retires S(ct) if needed; barrier; B(ct) loads;
    // S(ct+2) issued youngest; pre-compute wait vmcnt(2) completes B(ct)
    // while leaving S(ct+2) in flight (2 phases of slack per e-tile).
#define PHASE(CT) do {                                                          \
        asm volatile("s_waitcnt vmcnt(2)" ::: "memory");                        \
        __builtin_amdgcn_sched_barrier(0);                                      \
        __builtin_amdgcn_s_barrier();                                           \
        __builtin_amdgcn_sched_barrier(0);                                      \
        LOADB(CT);                                                              \
        __builtin_amdgcn_sched_barrier(0);                                      \
        if ((CT) < 6) { STAGE((CT) + 2); }                                      \
        __builtin_amdgcn_sched_barrier(0);                                      \
        if ((CT) < 6) { asm volatile("s_waitcnt vmcnt(2)" ::: "memory"); }      \
        else          { asm volatile("s_waitcnt vmcnt(0)" ::: "memory"); }      \
        __builtin_amdgcn_sched_barrier(0);                                      \
        COMPUTE(CT);                                                            \
    } while (0)

    bf16x8 wB[8];

    // prologue: 2 tiles in flight
    STAGE(0);
    STAGE(1);
    __builtin_amdgcn_sched_barrier(0);

    PHASE(0);
    PHASE(1);
    PHASE(2);
    PHASE(3);
    PHASE(4);
    PHASE(5);
    PHASE(6);
    PHASE(7);
#undef PHASE
#undef COMPUTE
#undef LOADB
#undef STAGE

    // ---- epilogue: scores s[j] = sum_d (E2[j,d]+be[d])*Q[d]*K[j,d] ----
    float q_l[4], be_l[4];
#pragma unroll
    for (int nf = 0; nf < 4; ++nf) {
        q_l[nf]  = Qw[(size_t)bi * HD + h * 64 + nf * 16 + c15];
        be_l[nf] = be[h * 64 + nf * 16 + c15];
    }
    const float* Kb  = Kw + ((size_t)b * NNODE + half * 64) * HD;
    const float* krw = k_RW + (size_t)bi * NNODE + half * 64;
#pragma unroll
    for (int mf = 0; mf < 4; ++mf) {
#pragma unroll
        for (int r = 0; r < 4; ++r) {
            int jl = mf * 16 + g * 4 + r;       // local j within half
            float s = 0.f;
#pragma unroll
            for (int nf = 0; nf < 4; ++nf) {
                float kv = Kb[(size_t)jl * HD + h * 64 + nf * 16 + c15];
                s += (acc[mf][nf][r] + be_l[nf]) * q_l[nf] * kv;
            }
            s += __shfl_xor(s, 1);
            s += __shfl_xor(s, 2);
            s += __shfl_xor(s, 4);
            s += __shfl_xor(s, 8);
            if (c15 == 0)
                s_lds[h][jl] = __expf(fminf(fmaxf(s, -5.f), 5.f)) * krw[jl];
        }
    }

    // ---- PV partials over own j-half (wave-private s_lds row) ----
    const float* Vb = Vw + ((size_t)b * NNODE + half * 64) * HD + h * 64 + l;
    float o = 0.f, den = 0.f;
#pragma unroll 4
    for (int jl = 0; jl < 64; ++jl) {
        float sv = s_lds[h][jl];
        o = fmaf(sv, Vb[(size_t)jl * HD], o);
        den += sv;
    }
    PN[((size_t)bx * 8 + h) * 64 + l] = o;
    if (l == 0) PD[(size_t)bx * 8 + h] = den;
}

// ---------------------------------------------------------------------------
// Kernel 4: combine the two j-half partials and normalize.
// ---------------------------------------------------------------------------
__global__ __launch_bounds__(512) void k_norm(
    const float* __restrict__ PN, const float* __restrict__ PD,
    float* __restrict__ out)
{
    const int bi = blockIdx.x;
    const int t  = threadIdx.x;
    const int h  = t >> 6;
    const int d  = t & 63;
    size_t r0 = ((size_t)(bi * 2 + 0) * 8 + h);
    size_t r1 = ((size_t)(bi * 2 + 1) * 8 + h);
    float num = PN[r0 * 64 + d] + PN[r1 * 64 + d];
    float den = fmaxf(PD[r0] + PD[r1], 1e-6f);
    out[(size_t)bi * HD + h * 64 + d] = num / den;
}

// ---------------------------------------------------------------------------
extern "C" void kernel_launch(void* const* d_in, const int* in_sizes, int n_in,
                              void* d_out, int out_size, void* d_ws, size_t ws_size,
                              hipStream_t stream) {
    const float* hin = (const float*)d_in[0];
    const float* e   = (const float*)d_in[1];
    const float* krw = (const float*)d_in[2];
    const float* Wq  = (const float*)d_in[3];
    const float* bq  = (const float*)d_in[4];
    const float* Wk  = (const float*)d_in[5];
    const float* bk  = (const float*)d_in[6];
    const float* We  = (const float*)d_in[7];
    const float* be  = (const float*)d_in[8];
    const float* Wv  = (const float*)d_in[9];
    const float* bv  = (const float*)d_in[10];
    float* out = (float*)d_out;

    char* ws = (char*)d_ws;
    unsigned short* WT  = (unsigned short*)ws;                   // 2 MB (slices 1..3)
    float* Q  = (float*)(ws + (2ull << 20));                     // 2 MB
    float* K  = (float*)(ws + (4ull << 20));                     // 2 MB
    float* V  = (float*)(ws + (6ull << 20));                     // 2 MB
    unsigned short* WTB = (unsigned short*)(ws + (8ull << 20));  // 512 KB
    float* PN = (float*)(ws + (9ull << 20));                     // 4 MB
    float* PD = (float*)(ws + (13ull << 20));                    // 64 KB

    k_wt  <<<dim3(8, 8, 3), dim3(256), 0, stream>>>(Wq, Wk, Wv, WT);
    k_wtb <<<dim3(8, 8),    dim3(256), 0, stream>>>(We, WTB);
    k_qkv <<<dim3(16, 8, 3), dim3(256), 0, stream>>>(hin, WT, bq, bk, bv, Q, K, V);
    k_main<<<dim3(2048), dim3(512), 0, stream>>>(e, krw, WTB, be, Q, K, V, PN, PD);
    k_norm<<<dim3(1024), dim3(512), 0, stream>>>(PN, PD, out);
}